// Round 18
// baseline (128.020 us; speedup 1.0000x reference)
//
#include <hip/hip_runtime.h>
#include <math.h>

// Problem constants
#define BATCH 8
#define NPIX 1024   // 32*32

typedef __attribute__((ext_vector_type(8))) short short8v;
typedef __attribute__((ext_vector_type(4))) float f32x4;

__device__ inline unsigned short f2bf(float x) {  // fp32 -> bf16 RNE
  unsigned int u = __float_as_uint(x);
  return (unsigned short)((u + 0x7FFFu + ((u >> 16) & 1u)) >> 16);
}
__device__ inline float bf2f(unsigned short h) {
  return __uint_as_float((unsigned int)h << 16);
}
__device__ inline unsigned long long pack4bf(float a, float b, float c, float d) {
  return (unsigned long long)(unsigned short)f2bf(a) |
         ((unsigned long long)(unsigned short)f2bf(b) << 16) |
         ((unsigned long long)(unsigned short)f2bf(c) << 32) |
         ((unsigned long long)(unsigned short)f2bf(d) << 48);
}

// ---------------------------------------------------------------------------
// MFMA bf16 GEMM.  Output modes:
//  0: fp32 std to Y0 (+res)
//  1: bf16 std to Y0
//  2: transposed bf16 to Y0 [n][tOff+m] stride tStride; EMIT_HI: rows
//     m>=128 also fp32 std to Y1 (cv1's y1)
//  3: split: m0<384 -> fp32 std Y0 (qkvb); else bf16 transposed Y1 [n][m-384]
//  4: tproj+combine: val = acc+bias + g*y1 + (1-a)*dwconv(y1) + a*obv;
//     transposed bf16 to Y0 [n][tOff+m]
// A source: WF32 ? fp32 row-major (convert during staging) : bf16 arena.
// B source: XF32T ? fp32 [K][1024] rows (in-kernel transpose) : bf16 [n][k]
//           rows stride ldx.
// ---------------------------------------------------------------------------
template<int MODE, bool HAS_BIAS, bool HAS_RES, bool XF32T, bool WF32, bool EMIT_HI>
__global__ __launch_bounds__(256) void mgemm_kernel(
    const void* __restrict__ Wsrc, const void* __restrict__ Xsrc, int ldx,
    const float* __restrict__ bias, const float* __restrict__ res,
    void* __restrict__ Y0, void* __restrict__ Y1,
    int K, long sXT, long sY, long sR, int tStride, int tOff,
    const float* __restrict__ y1p, const short* __restrict__ pnumS,
    const float* __restrict__ pdenP, const float* __restrict__ sproj_bP,
    const float* __restrict__ dw_wP, const float* __restrict__ dw_bP,
    const float* __restrict__ gP, const float* __restrict__ alphaP) {
  __shared__ __align__(16) short As[64][40];
  __shared__ __align__(16) short Bs[64][40];
  const int b = blockIdx.z;
  const int n0 = blockIdx.x * 64, m0 = blockIdx.y * 64;
  const int tid = threadIdx.x;
  const int l = tid & 63, w = tid >> 6;
  const int wm = w >> 1, wn = w & 1;
  const int sr = tid >> 2, sko = (tid & 3) * 8;
  const int xr = tid >> 3, xcg = (tid & 7) * 8;  // XF32T staging map
  const int fr = l & 15, fk = (l >> 4) * 8;
  f32x4 acc[2][2] = {};
  for (int k0 = 0; k0 < K; k0 += 32) {
    if (WF32) {
      const float* Wf = (const float*)Wsrc;
      const float4 wa = *(const float4*)(Wf + (long)(m0 + sr) * K + k0 + sko);
      const float4 wbv = *(const float4*)(Wf + (long)(m0 + sr) * K + k0 + sko + 4);
      As[sr][sko + 0] = (short)f2bf(wa.x); As[sr][sko + 1] = (short)f2bf(wa.y);
      As[sr][sko + 2] = (short)f2bf(wa.z); As[sr][sko + 3] = (short)f2bf(wa.w);
      As[sr][sko + 4] = (short)f2bf(wbv.x); As[sr][sko + 5] = (short)f2bf(wbv.y);
      As[sr][sko + 6] = (short)f2bf(wbv.z); As[sr][sko + 7] = (short)f2bf(wbv.w);
    } else {
      *(uint4*)&As[sr][sko] =
          *(const uint4*)((const short*)Wsrc + (long)(m0 + sr) * K + k0 + sko);
    }
    if (XF32T) {
      const float* Xf = (const float*)Xsrc + (long)b * sXT;
      const float4 xa = *(const float4*)(Xf + (long)(k0 + xr) * 1024 + n0 + xcg);
      const float4 xb = *(const float4*)(Xf + (long)(k0 + xr) * 1024 + n0 + xcg + 4);
      Bs[xcg + 0][xr] = (short)f2bf(xa.x); Bs[xcg + 1][xr] = (short)f2bf(xa.y);
      Bs[xcg + 2][xr] = (short)f2bf(xa.z); Bs[xcg + 3][xr] = (short)f2bf(xa.w);
      Bs[xcg + 4][xr] = (short)f2bf(xb.x); Bs[xcg + 5][xr] = (short)f2bf(xb.y);
      Bs[xcg + 6][xr] = (short)f2bf(xb.z); Bs[xcg + 7][xr] = (short)f2bf(xb.w);
    } else {
      const short* Xb = (const short*)Xsrc + (long)b * sXT;
      *(uint4*)&Bs[sr][sko] = *(const uint4*)(Xb + (long)(n0 + sr) * ldx + k0 + sko);
    }
    __syncthreads();
    short8v a0 = *(short8v*)&As[wm * 32 + fr][fk];
    short8v a1 = *(short8v*)&As[wm * 32 + 16 + fr][fk];
    short8v b0 = *(short8v*)&Bs[wn * 32 + fr][fk];
    short8v b1 = *(short8v*)&Bs[wn * 32 + 16 + fr][fk];
    acc[0][0] = __builtin_amdgcn_mfma_f32_16x16x32_bf16(a0, b0, acc[0][0], 0, 0, 0);
    acc[0][1] = __builtin_amdgcn_mfma_f32_16x16x32_bf16(a0, b1, acc[0][1], 0, 0, 0);
    acc[1][0] = __builtin_amdgcn_mfma_f32_16x16x32_bf16(a1, b0, acc[1][0], 0, 0, 0);
    acc[1][1] = __builtin_amdgcn_mfma_f32_16x16x32_bf16(a1, b1, acc[1][1], 0, 0, 0);
    __syncthreads();
  }
#pragma unroll
  for (int tm = 0; tm < 2; tm++) {
    const int m_base = m0 + wm * 32 + tm * 16 + (l >> 4) * 4;
#pragma unroll
    for (int tn = 0; tn < 2; tn++) {
      const int n = n0 + wn * 32 + tn * 16 + (l & 15);
      float v0 = acc[tm][tn][0], v1 = acc[tm][tn][1];
      float v2 = acc[tm][tn][2], v3 = acc[tm][tn][3];
      if (HAS_BIAS) {
        v0 += bias[m_base]; v1 += bias[m_base + 1];
        v2 += bias[m_base + 2]; v3 += bias[m_base + 3];
      }
      if (HAS_RES) {
        v0 += res[(long)b * sR + (long)(m_base + 0) * 1024 + n];
        v1 += res[(long)b * sR + (long)(m_base + 1) * 1024 + n];
        v2 += res[(long)b * sR + (long)(m_base + 2) * 1024 + n];
        v3 += res[(long)b * sR + (long)(m_base + 3) * 1024 + n];
      }
      if (MODE == 0) {
        float* Y = (float*)Y0 + (long)b * sY + n;
        Y[(long)(m_base + 0) * 1024] = v0; Y[(long)(m_base + 1) * 1024] = v1;
        Y[(long)(m_base + 2) * 1024] = v2; Y[(long)(m_base + 3) * 1024] = v3;
      } else if (MODE == 1) {
        short* Y = (short*)Y0 + (long)b * sY + n;
        Y[(long)(m_base + 0) * 1024] = (short)f2bf(v0);
        Y[(long)(m_base + 1) * 1024] = (short)f2bf(v1);
        Y[(long)(m_base + 2) * 1024] = (short)f2bf(v2);
        Y[(long)(m_base + 3) * 1024] = (short)f2bf(v3);
      } else if (MODE == 2) {
        *(unsigned long long*)((short*)Y0 + ((long)b * 1024 + n) * tStride +
                               tOff + m_base) = pack4bf(v0, v1, v2, v3);
        if (EMIT_HI && m_base >= 128) {
          float* Y = (float*)Y1 + ((long)b * 128 + m_base - 128) * 1024 + n;
          Y[0] = v0; Y[1024] = v1; Y[2048] = v2; Y[3072] = v3;
        }
      } else if (MODE == 3) {
        if (m0 < 384) {
          float* Y = (float*)Y0 + (long)b * 384 * 1024 + (long)m_base * 1024 + n;
          Y[0] = v0; Y[1024] = v1; Y[2048] = v2; Y[3072] = v3;
        } else {
          *(unsigned long long*)((short*)Y1 + ((long)b * 1024 + n) * 384 +
                                 (m_base - 384)) = pack4bf(v0, v1, v2, v3);
        }
      } else {  // MODE 4: tproj + dw/ob/gate combine, transposed bf16 out
        const float aab = alphaP[b];
        const long ds_ = 8L * 1024;
        const long dbase = (long)b * 1024 + n;
        const float den = pdenP[dbase] + pdenP[dbase + ds_] +
                          pdenP[dbase + 2 * ds_] + pdenP[dbase + 3 * ds_];
        const long ns_ = 8L * 128 * 1024;
        const int hh = n >> 5, wc = n & 31;
        float tv[4] = {v0, v1, v2, v3};
        float outv[4];
#pragma unroll
        for (int i = 0; i < 4; i++) {
          int c = m_base + i;
          const float* img = y1p + ((long)b * 128 + c) * 1024;
          float s = dw_bP[c];
#pragma unroll
          for (int ky = 0; ky < 3; ky++) {
            int h2 = hh + ky - 1;
            if (h2 < 0 || h2 > 31) continue;
#pragma unroll
            for (int kx = 0; kx < 3; kx++) {
              int w2 = wc + kx - 1;
              if (w2 < 0 || w2 > 31) continue;
              s += img[h2 * 32 + w2] * dw_wP[c * 9 + ky * 3 + kx];
            }
          }
          long nb = ((long)b * 128 + c) * 1024 + n;
          float num = bf2f((unsigned short)pnumS[nb]) +
                      bf2f((unsigned short)pnumS[nb + ns_]) +
                      bf2f((unsigned short)pnumS[nb + 2 * ns_]) +
                      bf2f((unsigned short)pnumS[nb + 3 * ns_]);
          float obv = num / den + sproj_bP[c];
          outv[i] = tv[i] + gP[b * 128 + c] * img[n] + (1.f - aab) * s + aab * obv;
        }
        *(unsigned long long*)((short*)Y0 + ((long)b * 1024 + n) * tStride +
                               tOff + m_base) =
            pack4bf(outv[0], outv[1], outv[2], outv[3]);
      }
    }
  }
}

// ---------------------------------------------------------------------------
// FFT magnitude pooling + channel means over y1[b][c][n].  Block per (b,c).
// Piggyback: converts the 768x128 qkv|q|k|v weight concat to bf16 (qarena).
// ---------------------------------------------------------------------------
__global__ __launch_bounds__(256) void fftpool_kernel(
    const float* __restrict__ y1, float* __restrict__ pooled, float* __restrict__ m1,
    const float* __restrict__ qkv_w, const float* __restrict__ q_w,
    const float* __restrict__ k_w, const float* __restrict__ v_w,
    short* __restrict__ qarena) {
  const int bc = blockIdx.x;
  const int t = threadIdx.x;
  {  // weight conversion side-job (consumed by a later kernel)
    int gid = bc * 256 + t;
    if (gid < 98304) {
      float v;
      if (gid < 49152) v = qkv_w[gid];
      else {
        int jj = gid - 49152, wsel = jj >> 14, r = jj & 16383;
        v = (wsel == 0) ? q_w[r] : (wsel == 1) ? k_w[r] : v_w[r];
      }
      qarena[gid] = (short)f2bf(v);
    }
  }
  const float* img = y1 + (long)bc * NPIX;
  __shared__ float im[1024];
  __shared__ float Gr[32][17], Gi[32][17];
  __shared__ float cs[32], sn[32];
  __shared__ float red[256];
  if (t < 32) {
    float ang = -0.19634954084936207f * (float)t;  // -2*pi*t/32
    __sincosf(ang, &sn[t], &cs[t]);
  }
  float lsum = 0.f;
  for (int i = t; i < 1024; i += 256) { float v = img[i]; im[i] = v; lsum += v; }
  red[t] = lsum;
  __syncthreads();
  for (int s = 128; s > 0; s >>= 1) {
    if (t < s) red[t] += red[t + s];
    __syncthreads();
  }
  if (t == 0) m1[bc] = red[0] * (1.f / 1024.f);
  for (int i = t; i < 544; i += 256) {
    int h = i / 17, v = i % 17;
    float ar = 0.f, ai = 0.f;
    for (int w2 = 0; w2 < 32; w2++) {
      int k = (v * w2) & 31;
      float x = im[h * 32 + w2];
      ar += x * cs[k]; ai += x * sn[k];
    }
    Gr[h][v] = ar; Gi[h][v] = ai;
  }
  __syncthreads();
  float asum = 0.f;
  for (int i = t; i < 544; i += 256) {
    int u = i / 17, v = i % 17;
    float xr = 0.f, xi = 0.f;
    for (int h = 0; h < 32; h++) {
      int k = (u * h) & 31;
      float gr = Gr[h][v], gi = Gi[h][v];
      xr += gr * cs[k] - gi * sn[k];
      xi += gr * sn[k] + gi * cs[k];
    }
    asum += sqrtf(xr * xr + xi * xi);
  }
  red[t] = asum;
  __syncthreads();
  for (int s = 128; s > 0; s >>= 1) {
    if (t < s) red[t] += red[t + s];
    __syncthreads();
  }
  if (t == 0) pooled[bc] = red[0] * (1.f / (32.f * 544.f));
}

// ---------------------------------------------------------------------------
// Gates + zero maxvk (varmax accumulates via atomicMax after this).
// ---------------------------------------------------------------------------
__global__ __launch_bounds__(128) void gates_kernel(
    const float* __restrict__ pooled, const float* __restrict__ m1,
    const float* __restrict__ fm_w1, const float* __restrict__ fm_w2,
    const float* __restrict__ ca_w1, const float* __restrict__ ca_w2,
    const float* __restrict__ rt_w, const float* __restrict__ rt_b,
    float* __restrict__ g, float* __restrict__ alpha, float* __restrict__ maxvk) {
  const int b = blockIdx.x, t = threadIdx.x;
  __shared__ float h1[8], fwv[128], xsm[128], h2[8];
  if (t < 8) maxvk[b * 8 + t] = 0.f;
  const float* pb = pooled + b * 128;
  const float* mb = m1 + b * 128;
  if (t < 8) {
    float s = 0.f;
    for (int c = 0; c < 128; c++) s += pb[c] * fm_w1[t * 128 + c];
    h1[t] = fmaxf(s, 0.f);
  }
  __syncthreads();
  {
    float s = 0.f;
    for (int r = 0; r < 8; r++) s += h1[r] * fm_w2[t * 8 + r];
    float fw = 1.f / (1.f + __expf(-s));
    fwv[t] = fw; xsm[t] = fw * mb[t];
  }
  __syncthreads();
  if (t < 8) {
    float s = 0.f;
    for (int c = 0; c < 128; c++) s += xsm[c] * ca_w1[t * 128 + c];
    h2[t] = fmaxf(s, 0.f);
  }
  __syncthreads();
  {
    float s = 0.f;
    for (int r = 0; r < 8; r++) s += h2[r] * ca_w2[t * 8 + r];
    float ca = 1.f / (1.f + __expf(-s));
    g[b * 128 + t] = fwv[t] * ca;
  }
  if (t == 0) {
    float s = 0.f;
    for (int c = 0; c < 128; c++) s += mb[c] * rt_w[c];
    s += rt_b[0];
    alpha[b] = 1.f / (1.f + __expf(-s));
  }
}

// ---------------------------------------------------------------------------
// Variance of k/v head vectors (ddof=1), vTb emit, atomicMax(var_k) -> maxvk.
// Grid (64 bh, 4 n-chunks of 256).
// ---------------------------------------------------------------------------
__global__ __launch_bounds__(256) void varmax_kernel(
    const float* __restrict__ qkvb, float* __restrict__ var_k,
    float* __restrict__ var_v, float* __restrict__ maxvk,
    short* __restrict__ vTb) {
  const int bh = blockIdx.x;
  const int chunk = blockIdx.y;
  const int b = bh >> 3, h = bh & 7;
  __shared__ float red[256];
  __shared__ float trans[16][256];
  const int n = chunk * 256 + threadIdx.x;
  const float* kb = qkvb + ((long)b * 384 + 128 + h * 16) * NPIX;
  const float* vb = qkvb + ((long)b * 384 + 256 + h * 16) * NPIX;
  float xk[16], xv[16], sk = 0.f, sv = 0.f;
#pragma unroll
  for (int d = 0; d < 16; d++) {
    xk[d] = kb[(long)d * NPIX + n]; sk += xk[d];
    xv[d] = vb[(long)d * NPIX + n]; sv += xv[d];
  }
  float mk = sk * (1.f / 16.f), mv = sv * (1.f / 16.f);
  float vk_ = 0.f, vv_ = 0.f;
#pragma unroll
  for (int d = 0; d < 16; d++) {
    float a = xk[d] - mk; vk_ += a * a;
    float c = xv[d] - mv; vv_ += c * c;
  }
  vk_ *= (1.f / 15.f); vv_ *= (1.f / 15.f);
  var_k[(long)bh * NPIX + n] = vk_;
  var_v[(long)bh * NPIX + n] = vv_;
#pragma unroll
  for (int d = 0; d < 16; d++) trans[d][threadIdx.x] = xv[d];
  __syncthreads();
  {
    int d = threadIdx.x >> 4, mc = threadIdx.x & 15;
    __align__(16) short tmp[16];
#pragma unroll
    for (int e = 0; e < 16; e++) tmp[e] = (short)f2bf(trans[d][mc * 16 + e]);
    short* dst = vTb + ((long)bh * 16 + d) * 1024 + chunk * 256 + mc * 16;
    *(uint4*)dst = *(uint4*)tmp;
    *(uint4*)(dst + 8) = *(uint4*)(tmp + 8);
  }
  red[threadIdx.x] = vk_;
  __syncthreads();
  for (int s = 128; s > 0; s >>= 1) {
    if (threadIdx.x < s) red[threadIdx.x] = fmaxf(red[threadIdx.x], red[threadIdx.x + s]);
    __syncthreads();
  }
  if (threadIdx.x == 0)
    atomicMax((int*)(maxvk + bh), __float_as_int(red[0]));  // var_k >= 0
}

// ---------------------------------------------------------------------------
// MFMA stat attention -> tcT[b][n][h*16+d] bf16 (no partials).
// ---------------------------------------------------------------------------
__global__ __launch_bounds__(256) void stat_mfma_kernel(
    const short* __restrict__ vTb, const float* __restrict__ var_k,
    const float* __restrict__ var_v, const float* __restrict__ maxvk,
    short* __restrict__ tcT) {
  const int bh = blockIdx.x;
  const int b = bh >> 3, h = bh & 7;
  const int n0 = blockIdx.y * 64;
  const int tid = threadIdx.x;
  const int l = tid & 63, w = tid >> 6;
  const int ln = l & 15, lk = l >> 4;
  const int n = n0 + w * 16 + ln;
  __shared__ float vk[1024];
  for (int i = tid; i < 1024; i += 256) vk[i] = var_k[(long)bh * 1024 + i];
  const float cn = var_v[(long)bh * 1024 + n] * 0.25f;
  const float mv = maxvk[bh];
  const short* arow = vTb + ((long)bh * 16 + ln) * 1024 + lk * 8;
  __syncthreads();
  f32x4 acc = {};
  float psum = 0.f;
  for (int m0 = 0; m0 < 1024; m0 += 32) {
    short8v afrag = *(const short8v*)(arow + m0);
    short8v bfrag;
#pragma unroll
    for (int j = 0; j < 8; j++) {
      float wv = __expf(cn * (vk[m0 + lk * 8 + j] - mv));
      psum += wv;
      bfrag[j] = (short)f2bf(wv);
    }
    acc = __builtin_amdgcn_mfma_f32_16x16x32_bf16(afrag, bfrag, acc, 0, 0, 0);
  }
  psum += __shfl_xor(psum, 16);
  psum += __shfl_xor(psum, 32);
  const float inv = 1.f / psum;
  *(unsigned long long*)(tcT + ((long)b * 1024 + n) * 128 + h * 16 + lk * 4) =
      pack4bf(acc[0] * inv, acc[1] * inv, acc[2] * inv, acc[3] * inv);
}

// ---------------------------------------------------------------------------
// Bit-pack signs from sqkvT[b][n][c] (bf16, coalesced).
// ---------------------------------------------------------------------------
__global__ __launch_bounds__(256) void pack_kernel(
    const short* __restrict__ sqkvT,
    unsigned long long* __restrict__ qbits, unsigned long long* __restrict__ kbits) {
  const int wave = threadIdx.x >> 6, lane = threadIdx.x & 63;
  const long p = (long)blockIdx.x * 4 + wave;  // 0..8191 = b*1024+n
  const short* base = sqkvT + p * 384;
  unsigned long long q0 = __ballot(bf2f((unsigned short)base[lane]) > 0.f);
  unsigned long long q1 = __ballot(bf2f((unsigned short)base[64 + lane]) > 0.f);
  unsigned long long k0 = __ballot(bf2f((unsigned short)base[128 + lane]) > 0.f);
  unsigned long long k1 = __ballot(bf2f((unsigned short)base[192 + lane]) > 0.f);
  if (lane == 0) {
    qbits[p * 2] = q0; qbits[p * 2 + 1] = q1;
    kbits[p * 2] = k0; kbits[p * 2 + 1] = k1;
  }
}

// ---------------------------------------------------------------------------
// MFMA binary-attention GEMM with in-register w synthesis (K-split x4).
// bf16 partial numerators.
// ---------------------------------------------------------------------------
__global__ __launch_bounds__(256) void obgemm_kernel(
    const short* __restrict__ pvb, const unsigned long long* __restrict__ qbits,
    const unsigned long long* __restrict__ kbits, short* __restrict__ pnum,
    float* __restrict__ pden) {
  const int b = blockIdx.z;
  const int sp = blockIdx.y;
  const int n0 = blockIdx.x * 64;
  const int kb0 = sp * 256;
  __shared__ __align__(16) short As[128][40];
  __shared__ __align__(16) unsigned long long kbsh[256][2];
  const int tid = threadIdx.x;
  const int l = tid & 63, w = tid >> 6;
  const int ln = l & 15, lk = l >> 4;
  const int n = n0 + w * 16 + ln;
  const unsigned long long q0 = qbits[((long)b * 1024 + n) * 2];
  const unsigned long long q1 = qbits[((long)b * 1024 + n) * 2 + 1];
  *(uint4*)&kbsh[tid][0] = *(const uint4*)(kbits + ((long)b * 1024 + kb0 + tid) * 2);
  const float fs = 0.08838834764831845f;
  const int sc = tid >> 1, sh = (tid & 1) * 16;
  const short* pvrow = pvb + ((long)b * 128 + sc) * 1024 + kb0;
  f32x4 acc[8] = {};
  float psum = 0.f;
  for (int ks = 0; ks < 8; ks++) {  // 32 m per step
    *(uint4*)&As[sc][sh] = *(const uint4*)(pvrow + ks * 32 + sh);
    *(uint4*)&As[sc][sh + 8] = *(const uint4*)(pvrow + ks * 32 + sh + 8);
    __syncthreads();
    const int mloc = ks * 32 + lk * 8;
    short8v bfrag;
#pragma unroll
    for (int j = 0; j < 8; j++) {
      unsigned long long kw0 = kbsh[mloc + j][0];
      unsigned long long kw1 = kbsh[mloc + j][1];
      int ham = __popcll(kw0 ^ q0) + __popcll(kw1 ^ q1);
      float wv = __expf((float)(128 - 2 * ham) * fs);
      psum += wv;
      bfrag[j] = (short)f2bf(wv);
    }
#pragma unroll
    for (int ct = 0; ct < 8; ct++) {
      short8v afrag = *(short8v*)&As[ct * 16 + ln][lk * 8];
      acc[ct] = __builtin_amdgcn_mfma_f32_16x16x32_bf16(afrag, bfrag, acc[ct], 0, 0, 0);
    }
    __syncthreads();
  }
  short* dst = pnum + (((long)sp * 8 + b) * 128) * 1024 + n;
#pragma unroll
  for (int ct = 0; ct < 8; ct++)
#pragma unroll
    for (int i = 0; i < 4; i++)
      dst[(long)(ct * 16 + lk * 4 + i) * 1024] = (short)f2bf(acc[ct][i]);
  psum += __shfl_xor(psum, 16);
  psum += __shfl_xor(psum, 32);
  if (lk == 0)
    pden[((long)sp * 8 + b) * 1024 + n] = psum;
}

// ---------------------------------------------------------------------------
extern "C" void kernel_launch(void* const* d_in, const int* in_sizes, int n_in,
                              void* d_out, int out_size, void* d_ws, size_t ws_size,
                              hipStream_t stream) {
  const float* x = (const float*)d_in[0];
  const float* cv1_w = (const float*)d_in[1];
  const float* cv1_b = (const float*)d_in[2];
  const float* fm_w1 = (const float*)d_in[3];
  const float* fm_w2 = (const float*)d_in[4];
  const float* ca_w1 = (const float*)d_in[5];
  const float* ca_w2 = (const float*)d_in[6];
  const float* qkv_w = (const float*)d_in[7];
  const float* tproj_w = (const float*)d_in[8];
  const float* tproj_b = (const float*)d_in[9];
  const float* dw_w = (const float*)d_in[10];
  const float* dw_b = (const float*)d_in[11];
  const float* rt_w = (const float*)d_in[12];
  const float* rt_b = (const float*)d_in[13];
  const float* q_w = (const float*)d_in[14];
  const float* k_w = (const float*)d_in[15];
  const float* v_w = (const float*)d_in[16];
  const float* sproj_w = (const float*)d_in[17];
  const float* sproj_b = (const float*)d_in[18];
  const float* cv2_w = (const float*)d_in[19];
  const float* cv2_b = (const float*)d_in[20];
  float* out = (float*)d_out;

  char* wsp = (char*)d_ws;
  size_t off = 0;
  auto alloc = [&](size_t bytes) {
    void* p = wsp + off;
    off += (bytes + 255) & ~(size_t)255;
    return p;
  };
  float* qkvb = (float*)alloc(8UL * 384 * 1024 * 4);  // pnum (bf16) aliases head
  float* y1 = (float*)alloc(8UL * 128 * 1024 * 4);
  short* ycT = (short*)alloc(8UL * 1024 * 384 * 2);
  short* sqkvT = (short*)alloc(8UL * 1024 * 384 * 2);
  short* tcT = (short*)alloc(8UL * 1024 * 128 * 2);
  short* pvb = (short*)alloc(8UL * 128 * 1024 * 2);
  short* qarena = (short*)alloc(98304UL * 2);
  short* vTb = (short*)alloc(64UL * 16 * 1024 * 2);
  float* pden = (float*)alloc(4UL * 8 * 1024 * 4);
  float* var_k = (float*)alloc(8UL * 8 * 1024 * 4);
  float* var_v = (float*)alloc(8UL * 8 * 1024 * 4);
  float* maxvk = (float*)alloc(64 * 4);
  float* pooled = (float*)alloc(1024 * 4);
  float* m1 = (float*)alloc(1024 * 4);
  float* g = (float*)alloc(1024 * 4);
  float* alpha = (float*)alloc(8 * 4);
  unsigned long long* qbits = (unsigned long long*)alloc(8192UL * 2 * 8);
  unsigned long long* kbits = (unsigned long long*)alloc(8192UL * 2 * 8);
  short* pnum = (short*)qkvb;  // 8.4MB bf16 partials; qkvb dead after varmax
  if (off > ws_size) return;

  dim3 blk(256);
  // 1. cv1 (MODE2, XF32T, WF32, EMIT_HI): ycT[n][0..256] bf16 + y1 fp32
  mgemm_kernel<2, true, false, true, true, true><<<dim3(16, 4, 8), blk, 0, stream>>>(
      cv1_w, x, 0, cv1_b, nullptr, ycT, y1, 256, 256L * 1024, 0, 0, 384, 0,
      nullptr, nullptr, nullptr, nullptr, nullptr, nullptr, nullptr, nullptr);
  // 2. FFT pooling + channel means (+ qkv weight arena conversion)
  fftpool_kernel<<<dim3(1024), blk, 0, stream>>>(y1, pooled, m1, qkv_w, q_w,
                                                 k_w, v_w, qarena);
  // 3. gates (+ maxvk zero)
  gates_kernel<<<dim3(8), dim3(128), 0, stream>>>(pooled, m1, fm_w1, fm_w2,
                                                  ca_w1, ca_w2, rt_w, rt_b, g,
                                                  alpha, maxvk);
  // 4. merged qkv + spatial-qkv projection (MODE3, M=768, arena A)
  mgemm_kernel<3, false, false, false, false, false><<<dim3(16, 12, 8), blk, 0, stream>>>(
      qarena, ycT + 128, 384, nullptr, nullptr, qkvb, sqkvT, 128, 1024L * 384,
      0, 0, 0, 0, nullptr, nullptr, nullptr, nullptr, nullptr, nullptr,
      nullptr, nullptr);
  // 5. variances + vTb + atomic maxvk  (grid 64x4)
  varmax_kernel<<<dim3(64, 4), blk, 0, stream>>>(qkvb, var_k, var_v, maxvk, vTb);
  // 6. MFMA stat attention -> tcT
  stat_mfma_kernel<<<dim3(64, 16), blk, 0, stream>>>(vTb, var_k, var_v, maxvk, tcT);
  // 7. sign pack
  pack_kernel<<<dim3(2048), blk, 0, stream>>>(sqkvT, qbits, kbits);
  // 7b. pv = sproj_w @ vv (MODE1 bf16 out, WF32)
  mgemm_kernel<1, false, false, false, true, false><<<dim3(16, 2, 8), blk, 0, stream>>>(
      sproj_w, sqkvT + 256, 384, nullptr, nullptr, pvb, nullptr, 128,
      1024L * 384, 128L * 1024, 0, 0, 0, nullptr, nullptr, nullptr, nullptr,
      nullptr, nullptr, nullptr, nullptr);
  // 8. MFMA binary-attention GEMM -> bf16 partials
  obgemm_kernel<<<dim3(16, 4, 8), blk, 0, stream>>>(pvb, qbits, kbits, pnum, pden);
  // 9. tproj + dw/ob/gate combine (MODE4, WF32) -> ycT[n][256..384]
  mgemm_kernel<4, true, false, false, true, false><<<dim3(16, 2, 8), blk, 0, stream>>>(
      tproj_w, tcT, 128, tproj_b, nullptr, ycT, nullptr, 128, 1024L * 128, 0,
      0, 384, 256, y1, pnum, pden, sproj_b, dw_w, dw_b, g, alpha);
  // 10. cv2 (MODE0, WF32) + residual
  mgemm_kernel<0, true, true, false, true, false><<<dim3(16, 4, 8), blk, 0, stream>>>(
      cv2_w, ycT, 384, cv2_b, x, out, nullptr, 384, 1024L * 384, 256L * 1024,
      256L * 1024, 0, 0, nullptr, nullptr, nullptr, nullptr, nullptr, nullptr,
      nullptr, nullptr);
}

// Round 19
// 120.813 us; speedup vs baseline: 1.0597x; 1.0597x over previous
//
#include <hip/hip_runtime.h>
#include <math.h>

// Problem constants
#define BATCH 8
#define NPIX 1024   // 32*32

typedef __attribute__((ext_vector_type(8))) short short8v;
typedef __attribute__((ext_vector_type(4))) float f32x4;

__device__ inline unsigned short f2bf(float x) {  // fp32 -> bf16 RNE
  unsigned int u = __float_as_uint(x);
  return (unsigned short)((u + 0x7FFFu + ((u >> 16) & 1u)) >> 16);
}
__device__ inline float bf2f(unsigned short h) {
  return __uint_as_float((unsigned int)h << 16);
}
__device__ inline unsigned long long pack4bf(float a, float b, float c, float d) {
  return (unsigned long long)(unsigned short)f2bf(a) |
         ((unsigned long long)(unsigned short)f2bf(b) << 16) |
         ((unsigned long long)(unsigned short)f2bf(c) << 32) |
         ((unsigned long long)(unsigned short)f2bf(d) << 48);
}

// ---------------------------------------------------------------------------
// Weights -> bf16 arena:
// [0,65536) cv1 | [65536,163840) qkv|q|k|v (768x128) | [163840,180224) tproj
// [180224,196608) sproj | [196608,294912) cv2
// ---------------------------------------------------------------------------
__global__ __launch_bounds__(256) void convw_kernel(
    const float* __restrict__ cv1_w, const float* __restrict__ qkv_w,
    const float* __restrict__ tproj_w, const float* __restrict__ sproj_w,
    const float* __restrict__ cv2_w, const float* __restrict__ q_w,
    const float* __restrict__ k_w, const float* __restrict__ v_w,
    short* __restrict__ wb) {
  int i = blockIdx.x * 256 + threadIdx.x;  // < 294912
  float v;
  if (i < 65536) v = cv1_w[i];
  else if (i < 163840) {
    int j = i - 65536;
    if (j < 49152) v = qkv_w[j];
    else {
      int jj = j - 49152, wsel = jj >> 14, r = jj & 16383;
      v = (wsel == 0) ? q_w[r] : (wsel == 1) ? k_w[r] : v_w[r];
    }
  }
  else if (i < 180224) v = tproj_w[i - 163840];
  else if (i < 196608) v = sproj_w[i - 180224];
  else v = cv2_w[i - 196608];
  wb[i] = (short)f2bf(v);
}

// ---------------------------------------------------------------------------
// MFMA bf16 GEMM.  Output modes:
//  0: fp32 std to Y0 (+res)
//  1: bf16 std to Y0
//  2: transposed bf16 to Y0 at [n][tOff+m], row stride tStride; if EMIT_HI,
//     also fp32 std rows m>=128 to Y1 (cv1's y1 side output)
//  3: qkv/skv split: m0<384 -> fp32 std Y0; else bf16 transposed Y1 [n][m-384]
// X source: XF32T ? fp32 [K][1024] rows (in-kernel transpose stage)
//                 : bf16 [n][k] rows with stride ldx.
// ---------------------------------------------------------------------------
template<int MODE, bool HAS_BIAS, bool HAS_RES, bool XF32T, bool EMIT_HI>
__global__ __launch_bounds__(256) void mgemm_kernel(
    const short* __restrict__ Wb, const void* __restrict__ Xsrc, int ldx,
    const float* __restrict__ bias, const float* __restrict__ res,
    void* __restrict__ Y0, void* __restrict__ Y1,
    int K, long sXT, long sY, long sR, int tStride, int tOff) {
  __shared__ __align__(16) short As[64][40];
  __shared__ __align__(16) short Bs[64][40];
  const int b = blockIdx.z;
  const int n0 = blockIdx.x * 64, m0 = blockIdx.y * 64;
  const int tid = threadIdx.x;
  const int l = tid & 63, w = tid >> 6;
  const int wm = w >> 1, wn = w & 1;
  const int sr = tid >> 2, sko = (tid & 3) * 8;
  const int xr = tid >> 3, xcg = (tid & 7) * 8;  // XF32T staging map
  const int fr = l & 15, fk = (l >> 4) * 8;
  f32x4 acc[2][2] = {};
  for (int k0 = 0; k0 < K; k0 += 32) {
    *(uint4*)&As[sr][sko] = *(const uint4*)(Wb + (long)(m0 + sr) * K + k0 + sko);
    if (XF32T) {
      const float* Xf = (const float*)Xsrc + (long)b * sXT;
      const float4 xa = *(const float4*)(Xf + (long)(k0 + xr) * 1024 + n0 + xcg);
      const float4 xb = *(const float4*)(Xf + (long)(k0 + xr) * 1024 + n0 + xcg + 4);
      Bs[xcg + 0][xr] = (short)f2bf(xa.x); Bs[xcg + 1][xr] = (short)f2bf(xa.y);
      Bs[xcg + 2][xr] = (short)f2bf(xa.z); Bs[xcg + 3][xr] = (short)f2bf(xa.w);
      Bs[xcg + 4][xr] = (short)f2bf(xb.x); Bs[xcg + 5][xr] = (short)f2bf(xb.y);
      Bs[xcg + 6][xr] = (short)f2bf(xb.z); Bs[xcg + 7][xr] = (short)f2bf(xb.w);
    } else {
      const short* Xb = (const short*)Xsrc + (long)b * sXT;
      *(uint4*)&Bs[sr][sko] = *(const uint4*)(Xb + (long)(n0 + sr) * ldx + k0 + sko);
    }
    __syncthreads();
    short8v a0 = *(short8v*)&As[wm * 32 + fr][fk];
    short8v a1 = *(short8v*)&As[wm * 32 + 16 + fr][fk];
    short8v b0 = *(short8v*)&Bs[wn * 32 + fr][fk];
    short8v b1 = *(short8v*)&Bs[wn * 32 + 16 + fr][fk];
    acc[0][0] = __builtin_amdgcn_mfma_f32_16x16x32_bf16(a0, b0, acc[0][0], 0, 0, 0);
    acc[0][1] = __builtin_amdgcn_mfma_f32_16x16x32_bf16(a0, b1, acc[0][1], 0, 0, 0);
    acc[1][0] = __builtin_amdgcn_mfma_f32_16x16x32_bf16(a1, b0, acc[1][0], 0, 0, 0);
    acc[1][1] = __builtin_amdgcn_mfma_f32_16x16x32_bf16(a1, b1, acc[1][1], 0, 0, 0);
    __syncthreads();
  }
#pragma unroll
  for (int tm = 0; tm < 2; tm++) {
    const int m_base = m0 + wm * 32 + tm * 16 + (l >> 4) * 4;
#pragma unroll
    for (int tn = 0; tn < 2; tn++) {
      const int n = n0 + wn * 32 + tn * 16 + (l & 15);
      float v0 = acc[tm][tn][0], v1 = acc[tm][tn][1];
      float v2 = acc[tm][tn][2], v3 = acc[tm][tn][3];
      if (HAS_BIAS) {
        v0 += bias[m_base]; v1 += bias[m_base + 1];
        v2 += bias[m_base + 2]; v3 += bias[m_base + 3];
      }
      if (HAS_RES) {
        v0 += res[(long)b * sR + (long)(m_base + 0) * 1024 + n];
        v1 += res[(long)b * sR + (long)(m_base + 1) * 1024 + n];
        v2 += res[(long)b * sR + (long)(m_base + 2) * 1024 + n];
        v3 += res[(long)b * sR + (long)(m_base + 3) * 1024 + n];
      }
      if (MODE == 0) {
        float* Y = (float*)Y0 + (long)b * sY + n;
        Y[(long)(m_base + 0) * 1024] = v0; Y[(long)(m_base + 1) * 1024] = v1;
        Y[(long)(m_base + 2) * 1024] = v2; Y[(long)(m_base + 3) * 1024] = v3;
      } else if (MODE == 1) {
        short* Y = (short*)Y0 + (long)b * sY + n;
        Y[(long)(m_base + 0) * 1024] = (short)f2bf(v0);
        Y[(long)(m_base + 1) * 1024] = (short)f2bf(v1);
        Y[(long)(m_base + 2) * 1024] = (short)f2bf(v2);
        Y[(long)(m_base + 3) * 1024] = (short)f2bf(v3);
      } else if (MODE == 2) {
        *(unsigned long long*)((short*)Y0 + ((long)b * 1024 + n) * tStride +
                               tOff + m_base) = pack4bf(v0, v1, v2, v3);
        if (EMIT_HI && m_base >= 128) {
          float* Y = (float*)Y1 + ((long)b * 128 + m_base - 128) * 1024 + n;
          Y[0] = v0; Y[1024] = v1; Y[2048] = v2; Y[3072] = v3;
        }
      } else {  // MODE 3
        if (m0 < 384) {
          float* Y = (float*)Y0 + (long)b * 384 * 1024 + (long)m_base * 1024 + n;
          Y[0] = v0; Y[1024] = v1; Y[2048] = v2; Y[3072] = v3;
        } else {
          *(unsigned long long*)((short*)Y1 + ((long)b * 1024 + n) * 384 +
                                 (m_base - 384)) = pack4bf(v0, v1, v2, v3);
        }
      }
    }
  }
}

// ---------------------------------------------------------------------------
// FFT magnitude pooling + channel means over y1[b][c][n].  Block per (b,c).
// ---------------------------------------------------------------------------
__global__ __launch_bounds__(256) void fftpool_kernel(
    const float* __restrict__ y1, float* __restrict__ pooled, float* __restrict__ m1) {
  const int bc = blockIdx.x;
  const float* img = y1 + (long)bc * NPIX;
  __shared__ float im[1024];
  __shared__ float Gr[32][17], Gi[32][17];
  __shared__ float cs[32], sn[32];
  __shared__ float red[256];
  const int t = threadIdx.x;
  if (t < 32) {
    float ang = -0.19634954084936207f * (float)t;  // -2*pi*t/32
    __sincosf(ang, &sn[t], &cs[t]);
  }
  float lsum = 0.f;
  for (int i = t; i < 1024; i += 256) { float v = img[i]; im[i] = v; lsum += v; }
  red[t] = lsum;
  __syncthreads();
  for (int s = 128; s > 0; s >>= 1) {
    if (t < s) red[t] += red[t + s];
    __syncthreads();
  }
  if (t == 0) m1[bc] = red[0] * (1.f / 1024.f);
  for (int i = t; i < 544; i += 256) {
    int h = i / 17, v = i % 17;
    float ar = 0.f, ai = 0.f;
    for (int w2 = 0; w2 < 32; w2++) {
      int k = (v * w2) & 31;
      float x = im[h * 32 + w2];
      ar += x * cs[k]; ai += x * sn[k];
    }
    Gr[h][v] = ar; Gi[h][v] = ai;
  }
  __syncthreads();
  float asum = 0.f;
  for (int i = t; i < 544; i += 256) {
    int u = i / 17, v = i % 17;
    float xr = 0.f, xi = 0.f;
    for (int h = 0; h < 32; h++) {
      int k = (u * h) & 31;
      float gr = Gr[h][v], gi = Gi[h][v];
      xr += gr * cs[k] - gi * sn[k];
      xi += gr * sn[k] + gi * cs[k];
    }
    asum += sqrtf(xr * xr + xi * xi);
  }
  red[t] = asum;
  __syncthreads();
  for (int s = 128; s > 0; s >>= 1) {
    if (t < s) red[t] += red[t + s];
    __syncthreads();
  }
  if (t == 0) pooled[bc] = red[0] * (1.f / (32.f * 544.f));
}

// ---------------------------------------------------------------------------
// Gates + zero maxvk (varmax accumulates via atomicMax after this).
// ---------------------------------------------------------------------------
__global__ __launch_bounds__(128) void gates_kernel(
    const float* __restrict__ pooled, const float* __restrict__ m1,
    const float* __restrict__ fm_w1, const float* __restrict__ fm_w2,
    const float* __restrict__ ca_w1, const float* __restrict__ ca_w2,
    const float* __restrict__ rt_w, const float* __restrict__ rt_b,
    float* __restrict__ g, float* __restrict__ alpha, float* __restrict__ maxvk) {
  const int b = blockIdx.x, t = threadIdx.x;
  __shared__ float h1[8], fwv[128], xsm[128], h2[8];
  if (t < 8) maxvk[b * 8 + t] = 0.f;
  const float* pb = pooled + b * 128;
  const float* mb = m1 + b * 128;
  if (t < 8) {
    float s = 0.f;
    for (int c = 0; c < 128; c++) s += pb[c] * fm_w1[t * 128 + c];
    h1[t] = fmaxf(s, 0.f);
  }
  __syncthreads();
  {
    float s = 0.f;
    for (int r = 0; r < 8; r++) s += h1[r] * fm_w2[t * 8 + r];
    float fw = 1.f / (1.f + __expf(-s));
    fwv[t] = fw; xsm[t] = fw * mb[t];
  }
  __syncthreads();
  if (t < 8) {
    float s = 0.f;
    for (int c = 0; c < 128; c++) s += xsm[c] * ca_w1[t * 128 + c];
    h2[t] = fmaxf(s, 0.f);
  }
  __syncthreads();
  {
    float s = 0.f;
    for (int r = 0; r < 8; r++) s += h2[r] * ca_w2[t * 8 + r];
    float ca = 1.f / (1.f + __expf(-s));
    g[b * 128 + t] = fwv[t] * ca;
  }
  if (t == 0) {
    float s = 0.f;
    for (int c = 0; c < 128; c++) s += mb[c] * rt_w[c];
    s += rt_b[0];
    alpha[b] = 1.f / (1.f + __expf(-s));
  }
}

// ---------------------------------------------------------------------------
// Variance of k/v head vectors (ddof=1), vTb emit, atomicMax(var_k)->maxvk.
// Grid (64 bh, 4 n-chunks of 256).
// ---------------------------------------------------------------------------
__global__ __launch_bounds__(256) void varmax_kernel(
    const float* __restrict__ qkvb, float* __restrict__ var_k,
    float* __restrict__ var_v, float* __restrict__ maxvk,
    short* __restrict__ vTb) {
  const int bh = blockIdx.x;
  const int chunk = blockIdx.y;
  const int b = bh >> 3, h = bh & 7;
  __shared__ float red[256];
  __shared__ float trans[16][256];
  const int n = chunk * 256 + threadIdx.x;
  const float* kb = qkvb + ((long)b * 384 + 128 + h * 16) * NPIX;
  const float* vb = qkvb + ((long)b * 384 + 256 + h * 16) * NPIX;
  float xk[16], xv[16], sk = 0.f, sv = 0.f;
#pragma unroll
  for (int d = 0; d < 16; d++) {
    xk[d] = kb[(long)d * NPIX + n]; sk += xk[d];
    xv[d] = vb[(long)d * NPIX + n]; sv += xv[d];
  }
  float mk = sk * (1.f / 16.f), mv = sv * (1.f / 16.f);
  float vk_ = 0.f, vv_ = 0.f;
#pragma unroll
  for (int d = 0; d < 16; d++) {
    float a = xk[d] - mk; vk_ += a * a;
    float c = xv[d] - mv; vv_ += c * c;
  }
  vk_ *= (1.f / 15.f); vv_ *= (1.f / 15.f);
  var_k[(long)bh * NPIX + n] = vk_;
  var_v[(long)bh * NPIX + n] = vv_;
#pragma unroll
  for (int d = 0; d < 16; d++) trans[d][threadIdx.x] = xv[d];
  __syncthreads();
  {
    int d = threadIdx.x >> 4, mc = threadIdx.x & 15;
    __align__(16) short tmp[16];
#pragma unroll
    for (int e = 0; e < 16; e++) tmp[e] = (short)f2bf(trans[d][mc * 16 + e]);
    short* dst = vTb + ((long)bh * 16 + d) * 1024 + chunk * 256 + mc * 16;
    *(uint4*)dst = *(uint4*)tmp;
    *(uint4*)(dst + 8) = *(uint4*)(tmp + 8);
  }
  red[threadIdx.x] = vk_;
  __syncthreads();
  for (int s = 128; s > 0; s >>= 1) {
    if (threadIdx.x < s) red[threadIdx.x] = fmaxf(red[threadIdx.x], red[threadIdx.x + s]);
    __syncthreads();
  }
  if (threadIdx.x == 0)
    atomicMax((int*)(maxvk + bh), __float_as_int(red[0]));  // var_k >= 0
}

// ---------------------------------------------------------------------------
// MFMA stat attention -> tcT[b][n][h*16+d] bf16 (no partials).
// ---------------------------------------------------------------------------
__global__ __launch_bounds__(256) void stat_mfma_kernel(
    const short* __restrict__ vTb, const float* __restrict__ var_k,
    const float* __restrict__ var_v, const float* __restrict__ maxvk,
    short* __restrict__ tcT) {
  const int bh = blockIdx.x;
  const int b = bh >> 3, h = bh & 7;
  const int n0 = blockIdx.y * 64;
  const int tid = threadIdx.x;
  const int l = tid & 63, w = tid >> 6;
  const int ln = l & 15, lk = l >> 4;
  const int n = n0 + w * 16 + ln;
  __shared__ float vk[1024];
  for (int i = tid; i < 1024; i += 256) vk[i] = var_k[(long)bh * 1024 + i];
  const float cn = var_v[(long)bh * 1024 + n] * 0.25f;
  const float mv = maxvk[bh];
  const short* arow = vTb + ((long)bh * 16 + ln) * 1024 + lk * 8;
  __syncthreads();
  f32x4 acc = {};
  float psum = 0.f;
  for (int m0 = 0; m0 < 1024; m0 += 32) {
    short8v afrag = *(const short8v*)(arow + m0);
    short8v bfrag;
#pragma unroll
    for (int j = 0; j < 8; j++) {
      float wv = __expf(cn * (vk[m0 + lk * 8 + j] - mv));
      psum += wv;
      bfrag[j] = (short)f2bf(wv);
    }
    acc = __builtin_amdgcn_mfma_f32_16x16x32_bf16(afrag, bfrag, acc, 0, 0, 0);
  }
  psum += __shfl_xor(psum, 16);
  psum += __shfl_xor(psum, 32);
  const float inv = 1.f / psum;
  *(unsigned long long*)(tcT + ((long)b * 1024 + n) * 128 + h * 16 + lk * 4) =
      pack4bf(acc[0] * inv, acc[1] * inv, acc[2] * inv, acc[3] * inv);
}

// ---------------------------------------------------------------------------
// Bit-pack signs from sqkvT[b][n][c] (bf16, coalesced).
// ---------------------------------------------------------------------------
__global__ __launch_bounds__(256) void pack_kernel(
    const short* __restrict__ sqkvT,
    unsigned long long* __restrict__ qbits, unsigned long long* __restrict__ kbits) {
  const int wave = threadIdx.x >> 6, lane = threadIdx.x & 63;
  const long p = (long)blockIdx.x * 4 + wave;  // 0..8191 = b*1024+n
  const short* base = sqkvT + p * 384;
  unsigned long long q0 = __ballot(bf2f((unsigned short)base[lane]) > 0.f);
  unsigned long long q1 = __ballot(bf2f((unsigned short)base[64 + lane]) > 0.f);
  unsigned long long k0 = __ballot(bf2f((unsigned short)base[128 + lane]) > 0.f);
  unsigned long long k1 = __ballot(bf2f((unsigned short)base[192 + lane]) > 0.f);
  if (lane == 0) {
    qbits[p * 2] = q0; qbits[p * 2 + 1] = q1;
    kbits[p * 2] = k0; kbits[p * 2 + 1] = k1;
  }
}

// ---------------------------------------------------------------------------
// MFMA binary-attention GEMM with in-register w synthesis (K-split x4).
// Partials written as bf16 (numerator of a weighted mean -> 0.4% rel ok).
// ---------------------------------------------------------------------------
__global__ __launch_bounds__(256) void obgemm_kernel(
    const short* __restrict__ pvb, const unsigned long long* __restrict__ qbits,
    const unsigned long long* __restrict__ kbits, short* __restrict__ pnum,
    float* __restrict__ pden) {
  const int b = blockIdx.z;
  const int sp = blockIdx.y;
  const int n0 = blockIdx.x * 64;
  const int kb0 = sp * 256;
  __shared__ __align__(16) short As[128][40];
  __shared__ __align__(16) unsigned long long kbsh[256][2];
  const int tid = threadIdx.x;
  const int l = tid & 63, w = tid >> 6;
  const int ln = l & 15, lk = l >> 4;
  const int n = n0 + w * 16 + ln;
  const unsigned long long q0 = qbits[((long)b * 1024 + n) * 2];
  const unsigned long long q1 = qbits[((long)b * 1024 + n) * 2 + 1];
  *(uint4*)&kbsh[tid][0] = *(const uint4*)(kbits + ((long)b * 1024 + kb0 + tid) * 2);
  const float fs = 0.08838834764831845f;
  const int sc = tid >> 1, sh = (tid & 1) * 16;
  const short* pvrow = pvb + ((long)b * 128 + sc) * 1024 + kb0;
  f32x4 acc[8] = {};
  float psum = 0.f;
  for (int ks = 0; ks < 8; ks++) {  // 32 m per step
    *(uint4*)&As[sc][sh] = *(const uint4*)(pvrow + ks * 32 + sh);
    *(uint4*)&As[sc][sh + 8] = *(const uint4*)(pvrow + ks * 32 + sh + 8);
    __syncthreads();
    const int mloc = ks * 32 + lk * 8;
    short8v bfrag;
#pragma unroll
    for (int j = 0; j < 8; j++) {
      unsigned long long kw0 = kbsh[mloc + j][0];
      unsigned long long kw1 = kbsh[mloc + j][1];
      int ham = __popcll(kw0 ^ q0) + __popcll(kw1 ^ q1);
      float wv = __expf((float)(128 - 2 * ham) * fs);
      psum += wv;
      bfrag[j] = (short)f2bf(wv);
    }
#pragma unroll
    for (int ct = 0; ct < 8; ct++) {
      short8v afrag = *(short8v*)&As[ct * 16 + ln][lk * 8];
      acc[ct] = __builtin_amdgcn_mfma_f32_16x16x32_bf16(afrag, bfrag, acc[ct], 0, 0, 0);
    }
    __syncthreads();
  }
  short* dst = pnum + (((long)sp * 8 + b) * 128) * 1024 + n;
#pragma unroll
  for (int ct = 0; ct < 8; ct++)
#pragma unroll
    for (int i = 0; i < 4; i++)
      dst[(long)(ct * 16 + lk * 4 + i) * 1024] = (short)f2bf(acc[ct][i]);
  psum += __shfl_xor(psum, 16);
  psum += __shfl_xor(psum, 32);
  if (lk == 0)
    pden[((long)sp * 8 + b) * 1024 + n] = psum;
}

// ---------------------------------------------------------------------------
// Fused depthwise 3x3 conv + ob reduce + combine (WITHOUT tproj part):
// attn = g*y1 + (1-a)*dwconv(y1) + a*obv.  tproj adds itself later (RES).
// ---------------------------------------------------------------------------
__global__ __launch_bounds__(256) void dwcombine_kernel(
    const float* __restrict__ y1, float* __restrict__ attn,
    const float* __restrict__ dw_w, const float* __restrict__ dw_b,
    const short* __restrict__ pnum, const float* __restrict__ pden,
    const float* __restrict__ sproj_b, const float* __restrict__ g,
    const float* __restrict__ alpha) {
  const int bc = blockIdx.x;
  const int b = bc >> 7, cx = bc & 127;
  const float* img = y1 + (long)bc * NPIX;
  float* dst = attn + (long)bc * NPIX;
  float w[9];
#pragma unroll
  for (int i = 0; i < 9; i++) w[i] = dw_w[cx * 9 + i];
  const float bias = dw_b[cx];
  const float a = alpha[b];
  const float gg = g[bc];
  const float sb = sproj_b[cx];
  const long ns = 8L * 128 * 1024;
  const long ds = 8L * 1024;
  const long nbase = (long)bc * 1024;
  const long dbase = (long)b * 1024;
  for (int i = threadIdx.x; i < 1024; i += 256) {
    int h = i >> 5, wx = i & 31;
    float s = bias;
#pragma unroll
    for (int ky = 0; ky < 3; ky++) {
      int hh = h + ky - 1;
      if (hh < 0 || hh > 31) continue;
#pragma unroll
      for (int kx = 0; kx < 3; kx++) {
        int ww2 = wx + kx - 1;
        if (ww2 < 0 || ww2 > 31) continue;
        s += img[hh * 32 + ww2] * w[ky * 3 + kx];
      }
    }
    float num = bf2f((unsigned short)pnum[nbase + i]) +
                bf2f((unsigned short)pnum[nbase + i + ns]) +
                bf2f((unsigned short)pnum[nbase + i + 2 * ns]) +
                bf2f((unsigned short)pnum[nbase + i + 3 * ns]);
    float den = pden[dbase + i] + pden[dbase + i + ds] +
                pden[dbase + i + 2 * ds] + pden[dbase + i + 3 * ds];
    float obv = num / den + sb;
    dst[i] = gg * img[i] + (1.f - a) * s + a * obv;
  }
}

// ---------------------------------------------------------------------------
extern "C" void kernel_launch(void* const* d_in, const int* in_sizes, int n_in,
                              void* d_out, int out_size, void* d_ws, size_t ws_size,
                              hipStream_t stream) {
  const float* x = (const float*)d_in[0];
  const float* cv1_w = (const float*)d_in[1];
  const float* cv1_b = (const float*)d_in[2];
  const float* fm_w1 = (const float*)d_in[3];
  const float* fm_w2 = (const float*)d_in[4];
  const float* ca_w1 = (const float*)d_in[5];
  const float* ca_w2 = (const float*)d_in[6];
  const float* qkv_w = (const float*)d_in[7];
  const float* tproj_w = (const float*)d_in[8];
  const float* tproj_b = (const float*)d_in[9];
  const float* dw_w = (const float*)d_in[10];
  const float* dw_b = (const float*)d_in[11];
  const float* rt_w = (const float*)d_in[12];
  const float* rt_b = (const float*)d_in[13];
  const float* q_w = (const float*)d_in[14];
  const float* k_w = (const float*)d_in[15];
  const float* v_w = (const float*)d_in[16];
  const float* sproj_w = (const float*)d_in[17];
  const float* sproj_b = (const float*)d_in[18];
  const float* cv2_w = (const float*)d_in[19];
  const float* cv2_b = (const float*)d_in[20];
  float* out = (float*)d_out;

  char* wsp = (char*)d_ws;
  size_t off = 0;
  auto alloc = [&](size_t bytes) {
    void* p = wsp + off;
    off += (bytes + 255) & ~(size_t)255;
    return p;
  };
  float* qkvb = (float*)alloc(8UL * 384 * 1024 * 4);  // pnum (bf16) aliases head
  float* y1 = (float*)alloc(8UL * 128 * 1024 * 4);
  float* attn = (float*)alloc(8UL * 128 * 1024 * 4);
  short* ycT = (short*)alloc(8UL * 1024 * 384 * 2);
  short* sqkvT = (short*)alloc(8UL * 1024 * 384 * 2);
  short* tcT = (short*)alloc(8UL * 1024 * 128 * 2);
  short* pvb = (short*)alloc(8UL * 128 * 1024 * 2);
  short* wb = (short*)alloc(294912UL * 2);
  short* vTb = (short*)alloc(64UL * 16 * 1024 * 2);
  float* pden = (float*)alloc(4UL * 8 * 1024 * 4);
  float* var_k = (float*)alloc(8UL * 8 * 1024 * 4);
  float* var_v = (float*)alloc(8UL * 8 * 1024 * 4);
  float* maxvk = (float*)alloc(64 * 4);
  float* pooled = (float*)alloc(1024 * 4);
  float* m1 = (float*)alloc(1024 * 4);
  float* g = (float*)alloc(1024 * 4);
  float* alpha = (float*)alloc(8 * 4);
  unsigned long long* qbits = (unsigned long long*)alloc(8192UL * 2 * 8);
  unsigned long long* kbits = (unsigned long long*)alloc(8192UL * 2 * 8);
  short* pnum = (short*)qkvb;  // 8.4MB bf16 partials inside qkvb (12.6MB),
                               // qkvb dead after varmax
  // weight arena offsets
  const short* cv1b = wb;
  const short* qsb = wb + 65536;
  const short* tprojb = wb + 163840;
  const short* sprojb = wb + 180224;
  const short* cv2b = wb + 196608;
  if (off > ws_size) return;

  dim3 blk(256);
  // 0. weights -> bf16 arena
  convw_kernel<<<dim3(1152), blk, 0, stream>>>(cv1_w, qkv_w, tproj_w, sproj_w,
                                               cv2_w, q_w, k_w, v_w, wb);
  // 1. cv1 (MFMA, MODE2 + XF32T: reads x fp32, in-kernel transpose):
  //    ycT[n][0..256] bf16 + y1 fp32
  mgemm_kernel<2, true, false, true, true><<<dim3(16, 4, 8), blk, 0, stream>>>(
      cv1b, x, 0, cv1_b, nullptr, ycT, y1, 256, 256L * 1024, 0, 0, 384, 0);
  // 2. FFT pooling + channel means (y1)
  fftpool_kernel<<<dim3(1024), blk, 0, stream>>>(y1, pooled, m1);
  // 3. gates (+ maxvk zero)
  gates_kernel<<<dim3(8), dim3(128), 0, stream>>>(pooled, m1, fm_w1, fm_w2,
                                                  ca_w1, ca_w2, rt_w, rt_b, g,
                                                  alpha, maxvk);
  // 4. merged qkv + spatial-qkv projection (MODE3, M=768)
  mgemm_kernel<3, false, false, false, false><<<dim3(16, 12, 8), blk, 0, stream>>>(
      qsb, ycT + 128, 384, nullptr, nullptr, qkvb, sqkvT, 128, 1024L * 384,
      0, 0, 0, 0);
  // 5. variances + vTb + atomic maxvk  (grid 64x4)
  varmax_kernel<<<dim3(64, 4), blk, 0, stream>>>(qkvb, var_k, var_v, maxvk, vTb);
  // 6. MFMA stat attention -> tcT
  stat_mfma_kernel<<<dim3(64, 16), blk, 0, stream>>>(vTb, var_k, var_v, maxvk, tcT);
  // 7. sign pack (coalesced from sqkvT)
  pack_kernel<<<dim3(2048), blk, 0, stream>>>(sqkvT, qbits, kbits);
  // 7b. pv = sproj_w @ vv (MFMA, MODE1 bf16 out)
  mgemm_kernel<1, false, false, false, false><<<dim3(16, 2, 8), blk, 0, stream>>>(
      sprojb, sqkvT + 256, 384, nullptr, nullptr, pvb, nullptr, 128,
      1024L * 384, 128L * 1024, 0, 0, 0);
  // 8. MFMA binary-attention GEMM -> bf16 partials
  obgemm_kernel<<<dim3(16, 4, 8), blk, 0, stream>>>(pvb, qbits, kbits, pnum, pden);
  // 9. dwcombine (freq + spat, WITHOUT tproj) -> attn
  dwcombine_kernel<<<dim3(1024), blk, 0, stream>>>(y1, attn, dw_w, dw_b, pnum,
                                                   pden, sproj_b, g, alpha);
  // 10. tproj (MFMA, MODE2: RES=attn, write transposed into ycT[n][256..384])
  mgemm_kernel<2, true, true, false, false><<<dim3(16, 2, 8), blk, 0, stream>>>(
      tprojb, tcT, 128, tproj_b, attn, ycT, nullptr, 128, 1024L * 128, 0,
      128L * 1024, 384, 256);
  // 11. cv2 (MFMA, MODE0) + residual
  mgemm_kernel<0, true, true, false, false><<<dim3(16, 4, 8), blk, 0, stream>>>(
      cv2b, ycT, 384, cv2_b, x, out, nullptr, 384, 1024L * 384, 256L * 1024,
      256L * 1024, 0, 0);
}